// Round 9
// baseline (140.625 us; speedup 1.0000x reference)
//
#include <hip/hip_runtime.h>

#define NPTS 1048576
#define NOUT 128
#define NPAR 64
#define BLOCK 512          // 8 waves: 4 producer + 4 consumer
#define CPB 1024           // points per block (producers: 256 threads x 4 pts)
#define STRH 136           // params LDS row stride in bf16 (272 B, rows cycle 8 bank groups)
#define NTILE 16           // 16 col-tiles of 8

typedef float vf4 __attribute__((ext_vector_type(4)));

__device__ __forceinline__ unsigned short f2bf(float f) {
    unsigned int u = __float_as_uint(f);
    u += 0x7fffu + ((u >> 16) & 1u);   // RNE
    return (unsigned short)(u >> 16);
}

__device__ __forceinline__ void bf2x(unsigned int u, float& lo, float& hi) {
    lo = __uint_as_float(u << 16);
    hi = __uint_as_float(u & 0xffff0000u);
}

__global__ __launch_bounds__(BLOCK, 4)   // 4 waves/EU -> 2 blocks/CU, 128-VGPR budget
void kan_kernel(const float* __restrict__ x,
                const float* __restrict__ params,
                float* __restrict__ out) {
    __shared__ unsigned short sH[NPAR * STRH];        // 17 KiB params bf16
    __shared__ unsigned short sRing[2][8 * CPB];      // 2 x 16 KiB result slots (bf16, [col][point])
    __shared__ int prodCnt[2];
    __shared__ int consCnt[2];

    const int tid = threadIdx.x;
    const int w   = tid >> 6;          // wave 0..7
    const int l   = tid & 63;

    if (tid == 0) { prodCnt[0] = prodCnt[1] = consCnt[0] = consCnt[1] = 0; }

    // ---- producer-side prologue (waves 0-3 = 256 threads) ----
    float b[4][4], sil[4];
    int rbase[4];
    if (w < 4) {
        const float4* p4 = (const float4*)params;
        #pragma unroll
        for (int g = tid; g < NPAR * (NOUT / 4); g += 256) {
            float4 v = p4[g];
            ushort4 h;
            h.x = f2bf(v.x); h.y = f2bf(v.y); h.z = f2bf(v.z); h.w = f2bf(v.w);
            *(ushort4*)&sH[(g >> 5) * STRH + (g & 31) * 4] = h;
        }

        const int base = blockIdx.x * CPB + tid * 4;
        const float4 xv = *(const float4*)(x + base);
        float xs[4] = {xv.x, xv.y, xv.z, xv.w};

        #pragma unroll
        for (int pp = 0; pp < 4; ++pp) {
            float xx = xs[pp];
            sil[pp] = xx / (1.0f + __expf(-xx));
            float inr = (xx >= -3.0f && xx < 3.0f) ? 1.0f : 0.0f;
            float u = (xx + 3.0f) * 10.0f;
            int si = (int)u;
            si = si < 0 ? 0 : (si > 59 ? 59 : si);

            float Ki   = -3.0f + 0.1f * (float)si;
            float Kim1 = -3.0f + 0.1f * (float)(si - 1 > 0 ? si - 1 : 0);
            float Kim2 = -3.0f + 0.1f * (float)(si - 2 > 0 ? si - 2 : 0);
            float Kip1 = -3.0f + 0.1f * (float)(si + 1);
            float Kip2 = -3.0f + 0.1f * (float)(si + 2 < 60 ? si + 2 : 60);
            float Kip3 = -3.0f + 0.1f * (float)(si + 3 < 60 ? si + 3 : 60);

            float l1 = xx - Ki,   r1 = Kip1 - xx;
            float l2 = xx - Kim1, r2 = Kip2 - xx;
            float l3 = xx - Kim2, r3 = Kip3 - xx;

            float N0 = 1.0f, N1, N2, N3, t, saved;
            t = N0 / (r1 + l1); N0 = r1 * t; N1 = l1 * t;
            t = N0 / (r1 + l2); N0 = r1 * t;          saved = l2 * t;
            t = N1 / (r2 + l1); N1 = saved + r2 * t;  N2    = l1 * t;
            t = N0 / (r1 + l3); N0 = r1 * t;          saved = l3 * t;
            t = N1 / (r2 + l2); N1 = saved + r2 * t;  saved = l2 * t;
            t = N2 / (r3 + l1); N2 = saved + r3 * t;  N3    = l1 * t;

            b[pp][0] = N0 * inr; b[pp][1] = N1 * inr;
            b[pp][2] = N2 * inr; b[pp][3] = N3 * inr;
            rbase[pp] = si;
        }
    }

    __syncthreads();   // flags zeroed + params staged

    if (w < 4) {
        // ================= PRODUCER =================
        #pragma unroll 1
        for (int t = 0; t < NTILE; ++t) {
            const int s = t & 1, g = t >> 1;
            if (g > 0) {
                // WAR: wait until all 4 consumer waves drained slot s, generation g-1
                while (__hip_atomic_load(&consCnt[s], __ATOMIC_ACQUIRE,
                                         __HIP_MEMORY_SCOPE_WORKGROUP) < 4 * g)
                    __builtin_amdgcn_s_sleep(1);
            }
            const int j0 = t << 3;

            uint4 u63 = *(const uint4*)&sH[63 * STRH + j0];
            float p63f[8];
            bf2x(u63.x, p63f[0], p63f[1]); bf2x(u63.y, p63f[2], p63f[3]);
            bf2x(u63.z, p63f[4], p63f[5]); bf2x(u63.w, p63f[6], p63f[7]);

            float a[4][8];
            #pragma unroll
            for (int pp = 0; pp < 4; ++pp) {
                const unsigned short* rp = &sH[rbase[pp] * STRH + j0];
                float sv = sil[pp];
                float acc[8];
                #pragma unroll
                for (int c = 0; c < 8; ++c) acc[c] = sv * p63f[c];
                #pragma unroll
                for (int r = 0; r < 4; ++r) {
                    uint4 q = *(const uint4*)(rp + r * STRH);
                    float f[8];
                    bf2x(q.x, f[0], f[1]); bf2x(q.y, f[2], f[3]);
                    bf2x(q.z, f[4], f[5]); bf2x(q.w, f[6], f[7]);
                    float br = b[pp][r];
                    #pragma unroll
                    for (int c = 0; c < 8; ++c) acc[c] = fmaf(br, f[c], acc[c]);
                }
                #pragma unroll
                for (int c = 0; c < 8; ++c) a[pp][c] = acc[c];
            }

            // stage transposed, bf16: ring[s][c][1024 pts], thread owns 4 consecutive pts
            #pragma unroll
            for (int c = 0; c < 8; ++c) {
                ushort4 h;
                h.x = f2bf(a[0][c]); h.y = f2bf(a[1][c]);
                h.z = f2bf(a[2][c]); h.w = f2bf(a[3][c]);
                *(ushort4*)&sRing[s][c * CPB + tid * 4] = h;
            }
            // ONE add per wave (lane 0). Release drains this wave's ds_writes first.
            if (l == 0)
                __hip_atomic_fetch_add(&prodCnt[s], 1, __ATOMIC_RELEASE,
                                       __HIP_MEMORY_SCOPE_WORKGROUP);
        }
    } else {
        // ================= CONSUMER =================
        const int cw = w - 4;                   // 0..3 -> rows 2cw, 2cw+1 of each tile
        float* outb = out + blockIdx.x * CPB;
        #pragma unroll 1
        for (int t = 0; t < NTILE; ++t) {
            const int s = t & 1, g = t >> 1;
            // RAW: wait until all 4 producer waves staged slot s, generation g
            while (__hip_atomic_load(&prodCnt[s], __ATOMIC_ACQUIRE,
                                     __HIP_MEMORY_SCOPE_WORKGROUP) < 4 * (g + 1))
                __builtin_amdgcn_s_sleep(1);

            const int j0 = t << 3;
            #pragma unroll
            for (int rr = 0; rr < 2; ++rr) {
                const int c = 2 * cw + rr;
                float* orow = outb + (size_t)(j0 + c) * NPTS;
                #pragma unroll
                for (int k = 0; k < 2; ++k) {
                    uint4 q = *(const uint4*)&sRing[s][c * CPB + k * 512 + l * 8];
                    float f[8];
                    bf2x(q.x, f[0], f[1]); bf2x(q.y, f[2], f[3]);
                    bf2x(q.z, f[4], f[5]); bf2x(q.w, f[6], f[7]);
                    vf4 v0 = { f[0], f[1], f[2], f[3] };
                    vf4 v1 = { f[4], f[5], f[6], f[7] };
                    *(vf4*)(orow + k * 512 + l * 8)     = v0;
                    *(vf4*)(orow + k * 512 + l * 8 + 4) = v1;
                }
            }
            // ONE add per wave (lane 0); release orders the slot reads before the count.
            if (l == 0)
                __hip_atomic_fetch_add(&consCnt[s], 1, __ATOMIC_RELEASE,
                                       __HIP_MEMORY_SCOPE_WORKGROUP);
        }
    }
}

extern "C" void kernel_launch(void* const* d_in, const int* in_sizes, int n_in,
                              void* d_out, int out_size, void* d_ws, size_t ws_size,
                              hipStream_t stream) {
    const float* x      = (const float*)d_in[0];
    const float* params = (const float*)d_in[1];
    float* out          = (float*)d_out;

    dim3 grid(NPTS / CPB);   // 1024 blocks
    kan_kernel<<<grid, BLOCK, 0, stream>>>(x, params, out);
}

// Round 10
// 123.642 us; speedup vs baseline: 1.1374x; 1.1374x over previous
//
#include <hip/hip_runtime.h>

#define NPTS 1048576
#define NOUT 128
#define NPAR 64
#define BLOCK 256
#define PPT 2              // points per thread -> 4 store buffers fit in VGPR budget
#define CPB (BLOCK * PPT)  // 512 points per block
#define STRH 136           // params LDS row stride in bf16 (272 B = 17*16)

typedef float vf2 __attribute__((ext_vector_type(2)));

__device__ __forceinline__ unsigned short f2bf(float f) {
    unsigned int u = __float_as_uint(f);
    u += 0x7fffu + ((u >> 16) & 1u);   // RNE
    return (unsigned short)(u >> 16);
}

__device__ __forceinline__ void bf2x(unsigned int u, float& lo, float& hi) {
    lo = __uint_as_float(u << 16);
    hi = __uint_as_float(u & 0xffff0000u);
}

__global__ __launch_bounds__(BLOCK, 4)
void kan_kernel(const float* __restrict__ x,
                const float* __restrict__ params,
                float* __restrict__ out) {
    __shared__ unsigned short sH[NPAR * STRH];

    const int tid = threadIdx.x;

    // Stage params [64][128] f32 -> LDS bf16
    {
        const float4* p4 = (const float4*)params;
        #pragma unroll
        for (int g = tid; g < NPAR * (NOUT / 4); g += BLOCK) {
            float4 v = p4[g];
            ushort4 h;
            h.x = f2bf(v.x); h.y = f2bf(v.y); h.z = f2bf(v.z); h.w = f2bf(v.w);
            *(ushort4*)&sH[(g >> 5) * STRH + (g & 31) * 4] = h;
        }
    }

    const int base = blockIdx.x * CPB + tid * PPT;
    const float2 xv = *(const float2*)(x + base);
    float xs[PPT] = {xv.x, xv.y};

    float b[PPT][4];
    float sil[PPT];
    int   rbase[PPT];

    #pragma unroll
    for (int pp = 0; pp < PPT; ++pp) {
        float xx = xs[pp];
        sil[pp] = xx / (1.0f + __expf(-xx));

        float inr = (xx >= -3.0f && xx < 3.0f) ? 1.0f : 0.0f;
        float u = (xx + 3.0f) * 10.0f;
        int si = (int)u;
        si = si < 0 ? 0 : (si > 59 ? 59 : si);

        float Ki   = -3.0f + 0.1f * (float)si;
        float Kim1 = -3.0f + 0.1f * (float)(si - 1 > 0 ? si - 1 : 0);
        float Kim2 = -3.0f + 0.1f * (float)(si - 2 > 0 ? si - 2 : 0);
        float Kip1 = -3.0f + 0.1f * (float)(si + 1);
        float Kip2 = -3.0f + 0.1f * (float)(si + 2 < 60 ? si + 2 : 60);
        float Kip3 = -3.0f + 0.1f * (float)(si + 3 < 60 ? si + 3 : 60);

        float l1 = xx - Ki,   r1 = Kip1 - xx;
        float l2 = xx - Kim1, r2 = Kip2 - xx;
        float l3 = xx - Kim2, r3 = Kip3 - xx;

        float N0 = 1.0f, N1, N2, N3, t, saved;
        t = N0 / (r1 + l1); N0 = r1 * t; N1 = l1 * t;
        t = N0 / (r1 + l2); N0 = r1 * t;          saved = l2 * t;
        t = N1 / (r2 + l1); N1 = saved + r2 * t;  N2    = l1 * t;
        t = N0 / (r1 + l3); N0 = r1 * t;          saved = l3 * t;
        t = N1 / (r2 + l2); N1 = saved + r2 * t;  saved = l2 * t;
        t = N2 / (r3 + l1); N2 = saved + r3 * t;  N3    = l1 * t;

        b[pp][0] = N0 * inr;
        b[pp][1] = N1 * inr;
        b[pp][2] = N2 * inr;
        b[pp][3] = N3 * inr;
        rbase[pp] = si;
    }

    __syncthreads();

    float* outc = out + base;

    // Four named store buffers (static indexing only — no runtime buffer index).
    float bA[PPT][8], bB[PPT][8], bC[PPT][8], bD[PPT][8];

// Compute 8-col tile TI (cols TI*8 .. TI*8+7) into BUF
#define COMPUTE(TI, BUF)                                                       \
    {                                                                          \
        const int j0 = (TI) << 3;                                              \
        uint4 u63 = *(const uint4*)&sH[63 * STRH + j0];                        \
        float p63f[8];                                                         \
        bf2x(u63.x, p63f[0], p63f[1]); bf2x(u63.y, p63f[2], p63f[3]);          \
        bf2x(u63.z, p63f[4], p63f[5]); bf2x(u63.w, p63f[6], p63f[7]);          \
        _Pragma("unroll")                                                      \
        for (int pp = 0; pp < PPT; ++pp) {                                     \
            const unsigned short* rp = &sH[rbase[pp] * STRH + j0];             \
            float s = sil[pp];                                                 \
            _Pragma("unroll")                                                  \
            for (int c = 0; c < 8; ++c) BUF[pp][c] = s * p63f[c];              \
            _Pragma("unroll")                                                  \
            for (int r = 0; r < 4; ++r) {                                      \
                uint4 q = *(const uint4*)(rp + r * STRH);                      \
                float f[8];                                                    \
                bf2x(q.x, f[0], f[1]); bf2x(q.y, f[2], f[3]);                  \
                bf2x(q.z, f[4], f[5]); bf2x(q.w, f[6], f[7]);                  \
                float br = b[pp][r];                                           \
                _Pragma("unroll")                                              \
                for (int c = 0; c < 8; ++c)                                    \
                    BUF[pp][c] = fmaf(br, f[c], BUF[pp][c]);                   \
            }                                                                  \
        }                                                                      \
    }

// Issue the 8 transposed float2 stores for tile TI from BUF
#define STORE(TI, BUF)                                                         \
    {                                                                          \
        float* rowp = outc + (size_t)((TI) << 3) * NPTS;                       \
        _Pragma("unroll")                                                      \
        for (int c = 0; c < 8; ++c) {                                          \
            vf2 v = { BUF[0][c], BUF[1][c] };                                  \
            *(vf2*)(rowp + (size_t)c * NPTS) = v;                              \
        }                                                                      \
    }

    // 4-buffer, 3-deep store pipeline. Each buffer's store -> overwrite
    // distance spans >=2 compute phases + 1 store batch, so ~24 stores
    // (~12 KiB/wave, ~192 KiB/CU at 16 waves) stay in flight -- mimicking
    // the fill kernel's never-blocked store issue.
    COMPUTE(0, bA);
    COMPUTE(1, bB);
    COMPUTE(2, bC);
    #pragma unroll
    for (int k = 0; k < 12; k += 4) {
        STORE(k + 0, bA);  COMPUTE(k + 3, bD);
        STORE(k + 1, bB);  COMPUTE(k + 4, bA);
        STORE(k + 2, bC);  COMPUTE(k + 5, bB);
        STORE(k + 3, bD);  COMPUTE(k + 6, bC);
    }
    STORE(12, bA);  COMPUTE(15, bD);
    STORE(13, bB);
    STORE(14, bC);
    STORE(15, bD);

#undef COMPUTE
#undef STORE
}

extern "C" void kernel_launch(void* const* d_in, const int* in_sizes, int n_in,
                              void* d_out, int out_size, void* d_ws, size_t ws_size,
                              hipStream_t stream) {
    const float* x      = (const float*)d_in[0];
    const float* params = (const float*)d_in[1];
    float* out          = (float*)d_out;

    dim3 grid(NPTS / CPB);   // 2048 blocks
    kan_kernel<<<grid, BLOCK, 0, stream>>>(x, params, out);
}

// Round 11
// 120.197 us; speedup vs baseline: 1.1700x; 1.0287x over previous
//
#include <hip/hip_runtime.h>

#define NPTS 1048576
#define NOUT 128
#define NPAR 64
#define BLOCK 256
#define PPT 4              // points per thread
#define CPB (BLOCK * PPT)  // 1024 points per block
#define STRH 136           // params LDS row stride in bf16 (272 B = 17*16, rows cycle 8 bank groups)
#define G 8                // output rows staged per tile
#define SST 1024           // staging row stride in f32 (both access phases conflict-free by construction)

typedef float vf4 __attribute__((ext_vector_type(4)));

__device__ __forceinline__ unsigned short f2bf(float f) {
    unsigned int u = __float_as_uint(f);
    u += 0x7fffu + ((u >> 16) & 1u);   // round-to-nearest-even
    return (unsigned short)(u >> 16);
}

__device__ __forceinline__ void bf2x(unsigned int u, float& lo, float& hi) {
    lo = __uint_as_float(u << 16);
    hi = __uint_as_float(u & 0xffff0000u);
}

__global__ __launch_bounds__(BLOCK, 4)
void kan_kernel(const float* __restrict__ x,
                const float* __restrict__ params,
                float* __restrict__ out) {
    __shared__ unsigned short sH[NPAR * STRH];  // 17.4 KB params (bf16)
    __shared__ float sS[G * SST];               // 32 KB output staging

    const int tid = threadIdx.x;

    // Stage params [64][128] f32 -> LDS bf16
    {
        const float4* p4 = (const float4*)params;
        #pragma unroll
        for (int g = tid; g < NPAR * (NOUT / 4); g += BLOCK) {
            float4 v = p4[g];
            ushort4 h;
            h.x = f2bf(v.x); h.y = f2bf(v.y); h.z = f2bf(v.z); h.w = f2bf(v.w);
            *(ushort4*)&sH[(g >> 5) * STRH + (g & 31) * 4] = h;
        }
    }

    const int base = blockIdx.x * CPB + tid * PPT;
    const float4 xv = *(const float4*)(x + base);
    float xs[PPT] = {xv.x, xv.y, xv.z, xv.w};

    float b[PPT][4];
    float sil[PPT];
    int   rbase[PPT];

    #pragma unroll
    for (int pp = 0; pp < PPT; ++pp) {
        float xx = xs[pp];
        sil[pp] = xx / (1.0f + __expf(-xx));

        float inr = (xx >= -3.0f && xx < 3.0f) ? 1.0f : 0.0f;
        float u = (xx + 3.0f) * 10.0f;
        int si = (int)u;
        si = si < 0 ? 0 : (si > 59 ? 59 : si);

        float Ki   = -3.0f + 0.1f * (float)si;
        float Kim1 = -3.0f + 0.1f * (float)(si - 1 > 0 ? si - 1 : 0);
        float Kim2 = -3.0f + 0.1f * (float)(si - 2 > 0 ? si - 2 : 0);
        float Kip1 = -3.0f + 0.1f * (float)(si + 1);
        float Kip2 = -3.0f + 0.1f * (float)(si + 2 < 60 ? si + 2 : 60);
        float Kip3 = -3.0f + 0.1f * (float)(si + 3 < 60 ? si + 3 : 60);

        float l1 = xx - Ki,   r1 = Kip1 - xx;
        float l2 = xx - Kim1, r2 = Kip2 - xx;
        float l3 = xx - Kim2, r3 = Kip3 - xx;

        float N0 = 1.0f, N1, N2, N3, t, saved;
        t = N0 / (r1 + l1); N0 = r1 * t; N1 = l1 * t;
        t = N0 / (r1 + l2); N0 = r1 * t;          saved = l2 * t;
        t = N1 / (r2 + l1); N1 = saved + r2 * t;  N2    = l1 * t;
        t = N0 / (r1 + l3); N0 = r1 * t;          saved = l3 * t;
        t = N1 / (r2 + l2); N1 = saved + r2 * t;  saved = l2 * t;
        t = N2 / (r3 + l1); N2 = saved + r3 * t;  N3    = l1 * t;

        b[pp][0] = N0 * inr;
        b[pp][1] = N1 * inr;
        b[pp][2] = N2 * inr;
        b[pp][3] = N3 * inr;
        rbase[pp] = si;
    }

    __syncthreads();   // params staged

    const int w = tid >> 6;       // wave id (0..3)
    const int l = tid & 63;       // lane

    #pragma unroll 1
    for (int j0 = 0; j0 < NOUT; j0 += G) {
        // ---- compute phase: 8 cols for 4 points ----
        uint4 u63 = *(const uint4*)&sH[63 * STRH + j0];
        float p63f[8];
        bf2x(u63.x, p63f[0], p63f[1]);
        bf2x(u63.y, p63f[2], p63f[3]);
        bf2x(u63.z, p63f[4], p63f[5]);
        bf2x(u63.w, p63f[6], p63f[7]);

        float a[PPT][8];
        #pragma unroll
        for (int pp = 0; pp < PPT; ++pp) {
            const unsigned short* rp = &sH[rbase[pp] * STRH + j0];
            float s = sil[pp];
            float acc[8];
            #pragma unroll
            for (int c = 0; c < 8; ++c) acc[c] = s * p63f[c];

            #pragma unroll
            for (int r = 0; r < 4; ++r) {
                uint4 q = *(const uint4*)(rp + r * STRH);
                float f[8];
                bf2x(q.x, f[0], f[1]); bf2x(q.y, f[2], f[3]);
                bf2x(q.z, f[4], f[5]); bf2x(q.w, f[6], f[7]);
                float br = b[pp][r];
                #pragma unroll
                for (int c = 0; c < 8; ++c) acc[c] = fmaf(br, f[c], acc[c]);
            }
            #pragma unroll
            for (int c = 0; c < 8; ++c) a[pp][c] = acc[c];
        }

        // write staging: row c holds this block's 1024 points for output row j0+c
        #pragma unroll
        for (int c = 0; c < 8; ++c) {
            vf4 v = { a[0][c], a[1][c], a[2][c], a[3][c] };
            *(vf4*)&sS[c * SST + tid * 4] = v;
        }

        __syncthreads();

        // ---- drain phase: j-major, one 4 KiB contiguous row burst per wave-row ----
        #pragma unroll
        for (int rr = 0; rr < 2; ++rr) {
            const int r = 2 * w + rr;
            float* orow = out + (size_t)(j0 + r) * NPTS + blockIdx.x * CPB;
            #pragma unroll
            for (int k = 0; k < 4; ++k) {
                vf4 v = *(const vf4*)&sS[r * SST + k * 256 + l * 4];
                *(vf4*)(orow + k * 256 + l * 4) = v;
            }
        }

        __syncthreads();   // staging reusable
    }
}

extern "C" void kernel_launch(void* const* d_in, const int* in_sizes, int n_in,
                              void* d_out, int out_size, void* d_ws, size_t ws_size,
                              hipStream_t stream) {
    const float* x      = (const float*)d_in[0];
    const float* params = (const float*)d_in[1];
    float* out          = (float*)d_out;

    dim3 grid(NPTS / CPB);   // 1024 blocks
    kan_kernel<<<grid, BLOCK, 0, stream>>>(x, params, out);
}